// Round 3
// baseline (1857.660 us; speedup 1.0000x reference)
//
#include <hip/hip_runtime.h>
#include <stdint.h>

// ---------------------------------------------------------------------------
// SamVisionAttention (B=256 windows, S=196, H=16, D=80, HIDDEN=1280), MI355X.
// Pipeline: cvt(X,Wqkv,Wproj,relh,relw) -> QKV GEMM (bf16 MFMA) ->
//           fused attention (rel-pos folded into QK^T as extra K-rows) ->
//           proj GEMM (f32 out).
// Workspace: ~503 MiB. X_bf16 buffer is reused as attn_out (same size).
// ---------------------------------------------------------------------------

typedef unsigned short u16;
typedef unsigned int   u32;
typedef short bf16x8  __attribute__((ext_vector_type(8)));
typedef float f32x4   __attribute__((ext_vector_type(4)));
typedef float f32x16  __attribute__((ext_vector_type(16)));

#define SCALE_Q   0.11180339887498949f   // 80^-0.5
#define INV_SCALE 8.944271909999159f     // 80^0.5

static __device__ __forceinline__ u16 f2bf(float f) {
  union { float f; u32 u; } a; a.f = f;
  u32 r = a.u + 0x7fffu + ((a.u >> 16) & 1u);
  return (u16)(r >> 16);
}
static __device__ __forceinline__ u32 packbf(float lo, float hi) {
  return (u32)f2bf(lo) | ((u32)f2bf(hi) << 16);
}

// global_load_lds with compile-safe address-space casts (via integer):
// generic->as1 is a no-op; generic->as3 takes the low 32 bits (LDS offset).
typedef __attribute__((address_space(1))) const u32 gas_u32;
typedef __attribute__((address_space(3))) u32 las_u32;
static __device__ __forceinline__ void load16_lds(const u16* g, void* l) {
  __builtin_amdgcn_global_load_lds((gas_u32*)(uintptr_t)g,
                                   (las_u32*)(u32)(uintptr_t)l, 16, 0, 0);
}

// --------------------------- f32 -> bf16 convert ---------------------------
__global__ void cvt_kernel(const float* __restrict__ src, u16* __restrict__ dst, int n4) {
  int i = blockIdx.x * blockDim.x + threadIdx.x;
  int str = gridDim.x * blockDim.x;
  for (; i < n4; i += str) {
    float4 v = ((const float4*)src)[i];
    uint2 o;
    o.x = packbf(v.x, v.y);
    o.y = packbf(v.z, v.w);
    ((uint2*)dst)[i] = o;
  }
}

// ------------------------------- GEMM (B^T) --------------------------------
// C[M,N] = A[M,K=1280] * Bm[N,K=1280]^T + bias[N]
// EPI=0: qkv epilogue -> scatter bf16 into q(*SCALE)/k/v [4096,196,80]
// EPI=1: proj epilogue -> f32 direct store to out[M,1280]
template <int EPI>
__global__ __launch_bounds__(256)
void gemm_bt(const u16* __restrict__ A, const u16* __restrict__ Bm,
             const float* __restrict__ bias,
             u16* __restrict__ qb, u16* __restrict__ kb, u16* __restrict__ vb,
             float* __restrict__ outp)
{
  alignas(16) __shared__ char smem[(EPI == 0) ? 34816 : 32768];
  u16* Alds = (u16*)smem;
  u16* Blds = (u16*)(smem + 16384);

  const int tid = threadIdx.x;
  const int w = tid >> 6, lane = tid & 63;
  const int wr = w >> 1, wc = w & 1;
  const int lr = lane & 15, lk = (lane >> 4) * 8;
  const int m0 = blockIdx.y * 128, n0 = blockIdx.x * 128;

  const u16* Ab = A  + (size_t)(m0 + (lane >> 3)) * 1280 + (lane & 7) * 8;
  const u16* Bb = Bm + (size_t)(n0 + (lane >> 3)) * 1280 + (lane & 7) * 8;

  f32x4 acc[4][4] = {};

  for (int kt = 0; kt < 20; ++kt) {
    __syncthreads();                       // previous tile's reads done
#pragma unroll
    for (int i = 0; i < 4; ++i) {
      const int rb = (i * 4 + w) * 8;      // 8 rows per wave-issue
      load16_lds(Ab + (size_t)rb * 1280 + kt * 64, smem + rb * 128);
      load16_lds(Bb + (size_t)rb * 1280 + kt * 64, smem + 16384 + rb * 128);
    }
    __syncthreads();                       // waits vmcnt(0): tiles resident
#pragma unroll
    for (int ks = 0; ks < 2; ++ks) {
      bf16x8 af[4], bfr[4];
#pragma unroll
      for (int mi = 0; mi < 4; ++mi)
        af[mi] = *(const bf16x8*)&Alds[(wr * 64 + mi * 16 + lr) * 64 + ks * 32 + lk];
#pragma unroll
      for (int ni = 0; ni < 4; ++ni)
        bfr[ni] = *(const bf16x8*)&Blds[(wc * 64 + ni * 16 + lr) * 64 + ks * 32 + lk];
#pragma unroll
      for (int mi = 0; mi < 4; ++mi)
#pragma unroll
        for (int ni = 0; ni < 4; ++ni)
          acc[mi][ni] = __builtin_amdgcn_mfma_f32_16x16x32_bf16(af[mi], bfr[ni], acc[mi][ni], 0, 0, 0);
    }
  }
  __syncthreads();

  if (EPI == 0) {
    // ---- bias + q-scale, bf16 -> LDS tile, then coalesced scatter to q/k/v
    const int which = n0 / 1280;                 // uniform per block (128|1280)
    const float sc = (which == 0) ? SCALE_Q : 1.0f;
    u16* Tlds = (u16*)smem;                      // [128][136] bf16 (aliases A/B)
#pragma unroll
    for (int mi = 0; mi < 4; ++mi)
#pragma unroll
      for (int ni = 0; ni < 4; ++ni) {
        float bv = bias[n0 + wc * 64 + ni * 16 + lr];
#pragma unroll
        for (int j = 0; j < 4; ++j) {
          float v = (acc[mi][ni][j] + bv) * sc;
          Tlds[(wr * 64 + mi * 16 + (lane >> 4) * 4 + j) * 136 + wc * 64 + ni * 16 + lr] = f2bf(v);
        }
      }
    __syncthreads();
    u16* dstp = (which == 0) ? qb : ((which == 1) ? kb : vb);
    const int b0 = m0 / 196, s0 = m0 - b0 * 196;
#pragma unroll
    for (int it = 0; it < 8; ++it) {
      int idx = it * 256 + tid;
      int r = idx >> 4, c = idx & 15;
      int4 vv = *(const int4*)&Tlds[r * 136 + c * 8];
      int s = s0 + r;
      int b = b0 + (s >= 196);
      s -= (s >= 196) ? 196 : 0;
      int n = n0 + c * 8;
      int nl = n - which * 1280;
      int h = nl / 80;
      int dd = nl - h * 80;
      *(int4*)&dstp[(((size_t)b * 16 + h) * 196 + s) * 80 + dd] = vv;
    }
  } else {
    // ---- proj: f32 direct coalesced store
#pragma unroll
    for (int mi = 0; mi < 4; ++mi)
#pragma unroll
      for (int ni = 0; ni < 4; ++ni) {
        int n = n0 + wc * 64 + ni * 16 + lr;
        float bv = bias[n];
#pragma unroll
        for (int j = 0; j < 4; ++j) {
          int m = m0 + wr * 64 + mi * 16 + (lane >> 4) * 4 + j;
          outp[(size_t)m * 1280 + n] = acc[mi][ni][j] + bv;
        }
      }
  }
}

// ------------------------------- attention ---------------------------------
// 1 block per (b,h), 7 waves x 32 q-rows. K' = [K(196); Rh(27); Rw(27); 0(6)]
// staged fully in LDS -> QK'^T over 8 tiles yields scores AND rel-pos dot
// tables G_h/G_w in one MFMA pass (swapped operands: rows=k', cols=q).
// G scattered to LDS (wave-local), gathered as per-q bias regs. Softmax is
// lane-local over regs + one shfl_xor(32); P packed to bf16 before PV.
__global__ __launch_bounds__(448)
void attn_kernel(const u16* __restrict__ qg, const u16* __restrict__ kg,
                 const u16* __restrict__ vg,
                 const u16* __restrict__ relhb, const u16* __restrict__ relwb,
                 u16* __restrict__ outb)
{
  alignas(16) __shared__ u16   Kp[256 * 88];   // 45056 B  K' rows, stride 88
  alignas(16) __shared__ u16   Vt[96 * 232];   // 44544 B  V^T [d][k], stride 232
  __shared__ float Gl[224 * 57];               // 51072 B  [q][jh 0..26 | jw 28..54]
  __shared__ float invL[224];

  const int bh = blockIdx.x, tid = threadIdx.x;
  const int w = tid >> 6, lane = tid & 63;
  const int hi = lane >> 5, l31 = lane & 31;

  const u16* Qg = qg + (size_t)bh * 15680;
  const u16* Kg = kg + (size_t)bh * 15680;
  const u16* Vg = vg + (size_t)bh * 15680;

  // ---- stage K' (256 rows x 80 cols as 10 int4/row) ----
  for (int idx = tid; idx < 2560; idx += 448) {
    int r = idx / 10, c = idx - (idx / 10) * 10;
    int4 v = make_int4(0, 0, 0, 0);
    if (r < 196)      v = *(const int4*)&Kg[r * 80 + c * 8];
    else if (r < 223) v = *(const int4*)&relhb[(r - 196) * 80 + c * 8];
    else if (r < 250) v = *(const int4*)&relwb[(r - 223) * 80 + c * 8];
    *(int4*)&Kp[r * 88 + c * 8] = v;
  }
  // ---- stage V^T (transpose pairs of k-rows into [d][k]) ----
  for (int idx = tid; idx < 980; idx += 448) {
    int kp = idx / 10, c = idx - (idx / 10) * 10;    // kp<98, c<10
    int4 v0 = *(const int4*)&Vg[(kp * 2) * 80 + c * 8];
    int4 v1 = *(const int4*)&Vg[(kp * 2 + 1) * 80 + c * 8];
    const u16* a = (const u16*)&v0; const u16* b = (const u16*)&v1;
#pragma unroll
    for (int jj = 0; jj < 8; ++jj)
      *(u32*)&Vt[(c * 8 + jj) * 232 + kp * 2] = (u32)a[jj] | ((u32)b[jj] << 16);
  }
  // zero pads: k-cols [196,232) for d<80, and d-rows [80,96) fully
  for (int idx = tid; idx < 80 * 18; idx += 448)
    *(u32*)&Vt[(idx / 18) * 232 + 196 + (idx - (idx / 18) * 18) * 2] = 0;
  for (int idx = tid; idx < 16 * 116; idx += 448)
    ((u32*)&Vt[(80 + idx / 116) * 232])[idx - (idx / 116) * 116] = 0;

  __syncthreads();   // the ONLY block-wide barrier

  // ---- Q fragments (global, rows clamped for pad lanes) ----
  const int qrow_l = w * 32 + l31;
  const int qc = (qrow_l < 196) ? qrow_l : 195;
  bf16x8 qf[5];
#pragma unroll
  for (int st = 0; st < 5; ++st)
    qf[st] = *(const bf16x8*)&Qg[qc * 80 + st * 16 + hi * 8];

  // ---- QK'^T (swapped): acc[t] rows=k' (crow), cols=q (lane&31) ----
  f32x16 acc[8] = {};
#pragma unroll
  for (int t = 0; t < 8; ++t)
#pragma unroll
    for (int st = 0; st < 5; ++st) {
      bf16x8 kf = *(const bf16x8*)&Kp[(t * 32 + l31) * 88 + st * 16 + hi * 8];
      acc[t] = __builtin_amdgcn_mfma_f32_32x32x16_bf16(kf, qf[st], acc[t], 0, 0, 0);
    }

  // ---- extract G_h/G_w from tiles 6,7 into Gl (wave-local rows) ----
#pragma unroll
  for (int r = 0; r < 16; ++r) {
    const int crow = (r & 3) + 8 * (r >> 2) + 4 * hi;
    const int k6 = 192 + crow;                 // in [192,224)
    if (k6 >= 223)      Gl[qrow_l * 57 + 28 + (k6 - 223)] = acc[6][r];
    else if (k6 >= 196) Gl[qrow_l * 57 + (k6 - 196)]      = acc[6][r];
    const int k7 = 224 + crow;                 // in [224,256)
    if (k7 < 250)       Gl[qrow_l * 57 + 28 + (k7 - 223)] = acc[7][r];
  }
  // same-wave scatter->gather: HW keeps per-wave DS order; fence the compiler
  __builtin_amdgcn_sched_barrier(0);

  // ---- gather per-q bias registers (same-wave ds order => no barrier) ----
  const int qh = qc / 14, qw = qc - qh * 14;
  float brg[28];
#pragma unroll
  for (int kh = 0; kh < 14; ++kh)
    brg[kh] = Gl[qrow_l * 57 + (qh - kh + 13)] * INV_SCALE;
#pragma unroll
  for (int kw_ = 0; kw_ < 14; ++kw_)
    brg[14 + kw_] = Gl[qrow_l * 57 + 28 + (qw - kw_ + 13)] * INV_SCALE;

  // ---- bias + mask + max ----
  float mx = -1e30f;
#pragma unroll
  for (int t = 0; t < 7; ++t)
#pragma unroll
    for (int r = 0; r < 16; ++r) {
      const int k0c = t * 32 + (r & 3) + 8 * (r >> 2);
      const int kh0 = k0c / 14, kw0 = k0c - kh0 * 14;
      const int kh1 = (k0c + 4) / 14, kw1 = (k0c + 4) - kh1 * 14;
      float bv = hi ? (brg[kh1] + brg[14 + kw1]) : (brg[kh0] + brg[14 + kw0]);
      int kk = k0c + 4 * hi;
      float sv = acc[t][r] + bv;
      sv = (kk < 196) ? sv : -1e30f;
      acc[t][r] = sv;
      mx = fmaxf(mx, sv);
    }
  mx = fmaxf(mx, __shfl_xor(mx, 32));

  // ---- exp + sum + pack P to bf16 A-fragments (frees the f32 scores) ----
  float sum = 0.f;
  u32 pw[7][8];
#pragma unroll
  for (int t = 0; t < 7; ++t) {
    float p[16];
#pragma unroll
    for (int r = 0; r < 16; ++r) { p[r] = __expf(acc[t][r] - mx); sum += p[r]; }
#pragma unroll
    for (int s2 = 0; s2 < 2; ++s2) {
      u32 a0 = packbf(p[s2 * 8 + 0], p[s2 * 8 + 1]);
      u32 a1 = packbf(p[s2 * 8 + 2], p[s2 * 8 + 3]);
      u32 b0 = packbf(p[s2 * 8 + 4], p[s2 * 8 + 5]);
      u32 b1 = packbf(p[s2 * 8 + 6], p[s2 * 8 + 7]);
      u32 xa0 = __shfl_xor(a0, 32), xa1 = __shfl_xor(a1, 32);
      u32 xb0 = __shfl_xor(b0, 32), xb1 = __shfl_xor(b1, 32);
      pw[t][s2 * 4 + 0] = hi ? xb0 : a0;
      pw[t][s2 * 4 + 1] = hi ? xb1 : a1;
      pw[t][s2 * 4 + 2] = hi ? b0 : xa0;
      pw[t][s2 * 4 + 3] = hi ? b1 : xa1;
    }
  }
  sum += __shfl_xor(sum, 32);
  if (lane < 32) invL[w * 32 + l31] = 1.0f / sum;
  __builtin_amdgcn_sched_barrier(0);

  // ---- PV: out[q][d] = sum_k P[q][k] V[k][d] ----
  f32x16 oacc[3] = {};
#pragma unroll
  for (int t = 0; t < 7; ++t)
#pragma unroll
    for (int s2 = 0; s2 < 2; ++s2) {
      union { u32 u[4]; bf16x8 v; } pf;
      pf.u[0] = pw[t][s2 * 4 + 0];
      pf.u[1] = pw[t][s2 * 4 + 1];
      pf.u[2] = pw[t][s2 * 4 + 2];
      pf.u[3] = pw[t][s2 * 4 + 3];
#pragma unroll
      for (int dt = 0; dt < 3; ++dt) {
        bf16x8 vf = *(const bf16x8*)&Vt[(dt * 32 + l31) * 232 + t * 32 + s2 * 16 + hi * 8];
        oacc[dt] = __builtin_amdgcn_mfma_f32_32x32x16_bf16(pf.v, vf, oacc[dt], 0, 0, 0);
      }
    }

  // ---- epilogue: divide by softmax sum, store bf16 [b, s, h*80+d] ----
  const int bb = bh >> 4, hh = bh & 15;
#pragma unroll
  for (int r = 0; r < 16; ++r) {
    int crow = (r & 3) + 8 * (r >> 2) + 4 * hi;
    int qrow = w * 32 + crow;
    if (qrow < 196) {
      float inv = invL[w * 32 + crow];
#pragma unroll
      for (int dt = 0; dt < 3; ++dt) {
        int d = dt * 32 + l31;
        if (d < 80) {
          size_t off = ((size_t)bb * 196 + qrow) * 1280 + hh * 80 + d;
          outb[off] = f2bf(oacc[dt][r] * inv);
        }
      }
    }
  }
}

// ------------------------------ launch -------------------------------------
extern "C" void kernel_launch(void* const* d_in, const int* in_sizes, int n_in,
                              void* d_out, int out_size, void* d_ws, size_t ws_size,
                              hipStream_t stream)
{
  (void)in_sizes; (void)n_in; (void)out_size; (void)ws_size;
  const float* hs    = (const float*)d_in[0];
  const float* wqkv  = (const float*)d_in[1];
  const float* bqkv  = (const float*)d_in[2];
  const float* wproj = (const float*)d_in[3];
  const float* bproj = (const float*)d_in[4];
  const float* relh  = (const float*)d_in[5];
  const float* relw  = (const float*)d_in[6];
  float* out = (float*)d_out;

  // workspace layout (bytes); total ~503 MiB
  char* ws = (char*)d_ws;
  u16* Xb    = (u16*)(ws);                 // 128,450,560  X_bf16, later attn_out
  u16* Wqb   = (u16*)(ws + 128450560);     //   9,830,400
  u16* Wpb   = (u16*)(ws + 138280960);     //   3,276,800
  u16* qb    = (u16*)(ws + 141557760);     // 128,450,560
  u16* kb    = (u16*)(ws + 270008320);     // 128,450,560
  u16* vb    = (u16*)(ws + 398458880);     // 128,450,560
  u16* relhb = (u16*)(ws + 526909440);     //       4,320
  u16* relwb = (u16*)(ws + 526913760);     //       4,320

  cvt_kernel<<<2048, 256, 0, stream>>>(hs,    Xb,  16056320);
  cvt_kernel<<<512,  256, 0, stream>>>(wqkv,  Wqb, 1228800);
  cvt_kernel<<<256,  256, 0, stream>>>(wproj, Wpb, 409600);
  cvt_kernel<<<1,    256, 0, stream>>>(relh,  relhb, 540);
  cvt_kernel<<<1,    256, 0, stream>>>(relw,  relwb, 540);

  gemm_bt<0><<<dim3(30, 392), 256, 0, stream>>>(Xb, Wqb, bqkv, qb, kb, vb, nullptr);

  attn_kernel<<<4096, 448, 0, stream>>>(qb, kb, vb, relhb, relwb, Xb);

  gemm_bt<1><<<dim3(10, 392), 256, 0, stream>>>(Xb, Wpb, bproj, nullptr, nullptr, nullptr, out);
}

// Round 7
// 1709.103 us; speedup vs baseline: 1.0869x; 1.0869x over previous
//
#include <hip/hip_runtime.h>
#include <stdint.h>

// ---------------------------------------------------------------------------
// SamVisionAttention (B=256 windows, S=196, H=16, D=80, HIDDEN=1280), MI355X.
// Pipeline: cvt(X,Wqkv,Wproj,relh,relw) -> QKV GEMM (bf16 MFMA) ->
//           fused attention (rel-pos folded into QK^T as extra K-rows) ->
//           proj GEMM (f32 out).
// R3..R6: GEMM LDS XOR-swizzle (T2: 16-way bank conflict -> 2-way) via
//     pre-swizzled global source + swizzled ds_read; XCD-aware block
//     swizzle (T1) for A-panel L2 locality. (R6 = R3 resubmitted: bench
//     has not run since R3 — acquisition timeouts / container failures.)
// ---------------------------------------------------------------------------

typedef unsigned short u16;
typedef unsigned int   u32;
typedef short bf16x8  __attribute__((ext_vector_type(8)));
typedef float f32x4   __attribute__((ext_vector_type(4)));
typedef float f32x16  __attribute__((ext_vector_type(16)));

#define SCALE_Q   0.11180339887498949f   // 80^-0.5
#define INV_SCALE 8.944271909999159f     // 80^0.5

static __device__ __forceinline__ u16 f2bf(float f) {
  union { float f; u32 u; } a; a.f = f;
  u32 r = a.u + 0x7fffu + ((a.u >> 16) & 1u);
  return (u16)(r >> 16);
}
static __device__ __forceinline__ u32 packbf(float lo, float hi) {
  return (u32)f2bf(lo) | ((u32)f2bf(hi) << 16);
}

// global_load_lds with compile-safe address-space casts (via integer):
typedef __attribute__((address_space(1))) const u32 gas_u32;
typedef __attribute__((address_space(3))) u32 las_u32;
static __device__ __forceinline__ void load16_lds(const u16* g, void* l) {
  __builtin_amdgcn_global_load_lds((gas_u32*)(uintptr_t)g,
                                   (las_u32*)(u32)(uintptr_t)l, 16, 0, 0);
}

// --------------------------- f32 -> bf16 convert ---------------------------
__global__ void cvt_kernel(const float* __restrict__ src, u16* __restrict__ dst, int n4) {
  int i = blockIdx.x * blockDim.x + threadIdx.x;
  int str = gridDim.x * blockDim.x;
  for (; i < n4; i += str) {
    float4 v = ((const float4*)src)[i];
    uint2 o;
    o.x = packbf(v.x, v.y);
    o.y = packbf(v.z, v.w);
    ((uint2*)dst)[i] = o;
  }
}

// ------------------------------- GEMM (B^T) --------------------------------
// C[M,N] = A[M,K=1280] * Bm[N,K=1280]^T + bias[N]
// LDS tiles [128][64] bf16, XOR-swizzled: LDS[r][s] holds global col16
// (s ^ (r&7)); staging pre-swizzles the GLOBAL source (LDS dest linear,
// global_load_lds constraint), fragment reads apply the same XOR.
// Grid is 1-D, XCD-swizzled: swz=(orig&7)*cpx+(orig>>3); bx=swz%nxb.
// EPI=0: qkv epilogue -> scatter bf16 into q(*SCALE)/k/v [4096,196,80]
// EPI=1: proj epilogue -> f32 direct store to out[M,1280]
template <int EPI>
__global__ __launch_bounds__(256)
void gemm_bt(const u16* __restrict__ A, const u16* __restrict__ Bm,
             const float* __restrict__ bias,
             u16* __restrict__ qb, u16* __restrict__ kb, u16* __restrict__ vb,
             float* __restrict__ outp, int nxb, int cpx)
{
  alignas(16) __shared__ char smem[(EPI == 0) ? 34816 : 32768];
  u16* Alds = (u16*)smem;
  u16* Blds = (u16*)(smem + 16384);

  const int tid = threadIdx.x;
  const int w = tid >> 6, lane = tid & 63;
  const int wr = w >> 1, wc = w & 1;
  const int lr = lane & 15, lc4 = lane >> 4;

  const int orig = blockIdx.x;
  const int swz = (orig & 7) * cpx + (orig >> 3);     // bijective: nwg%8==0
  const int bx = swz % nxb, by = swz / nxb;
  const int m0 = by * 128, n0 = bx * 128;

  // staging: lane covers row (lane>>3) of each 8-row chunk, 16B slot
  // (lane&7) in LDS; global col16 pre-swizzled by row&7 = lane>>3.
  const int srow = lane >> 3;
  const int scol = (lane & 7) ^ srow;
  const u16* Ab = A  + (size_t)(m0 + srow) * 1280 + scol * 8;
  const u16* Bb = Bm + (size_t)(n0 + srow) * 1280 + scol * 8;

  f32x4 acc[4][4] = {};

  for (int kt = 0; kt < 20; ++kt) {
    __syncthreads();                       // previous tile's reads done
#pragma unroll
    for (int i = 0; i < 4; ++i) {
      const int rb = (i * 4 + w) * 8;      // 8 rows per wave-issue
      load16_lds(Ab + (size_t)rb * 1280 + kt * 64, smem + rb * 128);
      load16_lds(Bb + (size_t)rb * 1280 + kt * 64, smem + 16384 + rb * 128);
    }
    __syncthreads();                       // waits vmcnt(0): tiles resident
#pragma unroll
    for (int ks = 0; ks < 2; ++ks) {
      bf16x8 af[4], bfr[4];
      const int c16 = ks * 4 + lc4;        // logical col16 0..7
#pragma unroll
      for (int mi = 0; mi < 4; ++mi) {
        const int row = wr * 64 + mi * 16 + lr;
        af[mi] = *(const bf16x8*)&Alds[row * 64 + (c16 ^ (lr & 7)) * 8];
      }
#pragma unroll
      for (int ni = 0; ni < 4; ++ni) {
        const int row = wc * 64 + ni * 16 + lr;
        bfr[ni] = *(const bf16x8*)&Blds[row * 64 + (c16 ^ (lr & 7)) * 8];
      }
#pragma unroll
      for (int mi = 0; mi < 4; ++mi)
#pragma unroll
        for (int ni = 0; ni < 4; ++ni)
          acc[mi][ni] = __builtin_amdgcn_mfma_f32_16x16x32_bf16(af[mi], bfr[ni], acc[mi][ni], 0, 0, 0);
    }
  }
  __syncthreads();

  if (EPI == 0) {
    // ---- bias + q-scale, bf16 -> LDS tile, then coalesced scatter to q/k/v
    const int which = n0 / 1280;                 // uniform per block (128|1280)
    const float sc = (which == 0) ? SCALE_Q : 1.0f;
    u16* Tlds = (u16*)smem;                      // [128][136] bf16 (aliases A/B)
#pragma unroll
    for (int mi = 0; mi < 4; ++mi)
#pragma unroll
      for (int ni = 0; ni < 4; ++ni) {
        float bv = bias[n0 + wc * 64 + ni * 16 + lr];
#pragma unroll
        for (int j = 0; j < 4; ++j) {
          float v = (acc[mi][ni][j] + bv) * sc;
          Tlds[(wr * 64 + mi * 16 + lc4 * 4 + j) * 136 + wc * 64 + ni * 16 + lr] = f2bf(v);
        }
      }
    __syncthreads();
    u16* dstp = (which == 0) ? qb : ((which == 1) ? kb : vb);
    const int b0 = m0 / 196, s0 = m0 - b0 * 196;
#pragma unroll
    for (int it = 0; it < 8; ++it) {
      int idx = it * 256 + tid;
      int r = idx >> 4, c = idx & 15;
      int4 vv = *(const int4*)&Tlds[r * 136 + c * 8];
      int s = s0 + r;
      int b = b0 + (s >= 196);
      s -= (s >= 196) ? 196 : 0;
      int n = n0 + c * 8;
      int nl = n - which * 1280;
      int h = nl / 80;
      int dd = nl - h * 80;
      *(int4*)&dstp[(((size_t)b * 16 + h) * 196 + s) * 80 + dd] = vv;
    }
  } else {
    // ---- proj: f32 direct coalesced store
#pragma unroll
    for (int mi = 0; mi < 4; ++mi)
#pragma unroll
      for (int ni = 0; ni < 4; ++ni) {
        int n = n0 + wc * 64 + ni * 16 + lr;
        float bv = bias[n];
#pragma unroll
        for (int j = 0; j < 4; ++j) {
          int m = m0 + wr * 64 + mi * 16 + lc4 * 4 + j;
          outp[(size_t)m * 1280 + n] = acc[mi][ni][j] + bv;
        }
      }
  }
}

// ------------------------------- attention ---------------------------------
// 1 block per (b,h), 7 waves x 32 q-rows. K' = [K(196); Rh(27); Rw(27); 0(6)]
// staged fully in LDS -> QK'^T over 8 tiles yields scores AND rel-pos dot
// tables G_h/G_w in one MFMA pass (swapped operands: rows=k', cols=q).
// G scattered to LDS (wave-local), gathered as per-q bias regs. Softmax is
// lane-local over regs + one shfl_xor(32); P packed to bf16 before PV.
__global__ __launch_bounds__(448)
void attn_kernel(const u16* __restrict__ qg, const u16* __restrict__ kg,
                 const u16* __restrict__ vg,
                 const u16* __restrict__ relhb, const u16* __restrict__ relwb,
                 u16* __restrict__ outb)
{
  alignas(16) __shared__ u16   Kp[256 * 88];   // 45056 B  K' rows, stride 88
  alignas(16) __shared__ u16   Vt[96 * 232];   // 44544 B  V^T [d][k], stride 232
  __shared__ float Gl[224 * 57];               // 51072 B  [q][jh 0..26 | jw 28..54]
  __shared__ float invL[224];

  const int bh = blockIdx.x, tid = threadIdx.x;
  const int w = tid >> 6, lane = tid & 63;
  const int hi = lane >> 5, l31 = lane & 31;

  const u16* Qg = qg + (size_t)bh * 15680;
  const u16* Kg = kg + (size_t)bh * 15680;
  const u16* Vg = vg + (size_t)bh * 15680;

  // ---- stage K' (256 rows x 80 cols as 10 int4/row) ----
  for (int idx = tid; idx < 2560; idx += 448) {
    int r = idx / 10, c = idx - (idx / 10) * 10;
    int4 v = make_int4(0, 0, 0, 0);
    if (r < 196)      v = *(const int4*)&Kg[r * 80 + c * 8];
    else if (r < 223) v = *(const int4*)&relhb[(r - 196) * 80 + c * 8];
    else if (r < 250) v = *(const int4*)&relwb[(r - 223) * 80 + c * 8];
    *(int4*)&Kp[r * 88 + c * 8] = v;
  }
  // ---- stage V^T (transpose pairs of k-rows into [d][k]) ----
  for (int idx = tid; idx < 980; idx += 448) {
    int kp = idx / 10, c = idx - (idx / 10) * 10;    // kp<98, c<10
    int4 v0 = *(const int4*)&Vg[(kp * 2) * 80 + c * 8];
    int4 v1 = *(const int4*)&Vg[(kp * 2 + 1) * 80 + c * 8];
    const u16* a = (const u16*)&v0; const u16* b = (const u16*)&v1;
#pragma unroll
    for (int jj = 0; jj < 8; ++jj)
      *(u32*)&Vt[(c * 8 + jj) * 232 + kp * 2] = (u32)a[jj] | ((u32)b[jj] << 16);
  }
  // zero pads: k-cols [196,232) for d<80, and d-rows [80,96) fully
  for (int idx = tid; idx < 80 * 18; idx += 448)
    *(u32*)&Vt[(idx / 18) * 232 + 196 + (idx - (idx / 18) * 18) * 2] = 0;
  for (int idx = tid; idx < 16 * 116; idx += 448)
    ((u32*)&Vt[(80 + idx / 116) * 232])[idx - (idx / 116) * 116] = 0;

  __syncthreads();   // the ONLY block-wide barrier

  // ---- Q fragments (global, rows clamped for pad lanes) ----
  const int qrow_l = w * 32 + l31;
  const int qc = (qrow_l < 196) ? qrow_l : 195;
  bf16x8 qf[5];
#pragma unroll
  for (int st = 0; st < 5; ++st)
    qf[st] = *(const bf16x8*)&Qg[qc * 80 + st * 16 + hi * 8];

  // ---- QK'^T (swapped): acc[t] rows=k' (crow), cols=q (lane&31) ----
  f32x16 acc[8] = {};
#pragma unroll
  for (int t = 0; t < 8; ++t)
#pragma unroll
    for (int st = 0; st < 5; ++st) {
      bf16x8 kf = *(const bf16x8*)&Kp[(t * 32 + l31) * 88 + st * 16 + hi * 8];
      acc[t] = __builtin_amdgcn_mfma_f32_32x32x16_bf16(kf, qf[st], acc[t], 0, 0, 0);
    }

  // ---- extract G_h/G_w from tiles 6,7 into Gl (wave-local rows) ----
#pragma unroll
  for (int r = 0; r < 16; ++r) {
    const int crow = (r & 3) + 8 * (r >> 2) + 4 * hi;
    const int k6 = 192 + crow;                 // in [192,224)
    if (k6 >= 223)      Gl[qrow_l * 57 + 28 + (k6 - 223)] = acc[6][r];
    else if (k6 >= 196) Gl[qrow_l * 57 + (k6 - 196)]      = acc[6][r];
    const int k7 = 224 + crow;                 // in [224,256)
    if (k7 < 250)       Gl[qrow_l * 57 + 28 + (k7 - 223)] = acc[7][r];
  }
  // same-wave scatter->gather: HW keeps per-wave DS order; fence the compiler
  __builtin_amdgcn_sched_barrier(0);

  // ---- gather per-q bias registers (same-wave ds order => no barrier) ----
  const int qh = qc / 14, qw = qc - qh * 14;
  float brg[28];
#pragma unroll
  for (int kh = 0; kh < 14; ++kh)
    brg[kh] = Gl[qrow_l * 57 + (qh - kh + 13)] * INV_SCALE;
#pragma unroll
  for (int kw_ = 0; kw_ < 14; ++kw_)
    brg[14 + kw_] = Gl[qrow_l * 57 + 28 + (qw - kw_ + 13)] * INV_SCALE;

  // ---- bias + mask + max ----
  float mx = -1e30f;
#pragma unroll
  for (int t = 0; t < 7; ++t)
#pragma unroll
    for (int r = 0; r < 16; ++r) {
      const int k0c = t * 32 + (r & 3) + 8 * (r >> 2);
      const int kh0 = k0c / 14, kw0 = k0c - kh0 * 14;
      const int kh1 = (k0c + 4) / 14, kw1 = (k0c + 4) - kh1 * 14;
      float bv = hi ? (brg[kh1] + brg[14 + kw1]) : (brg[kh0] + brg[14 + kw0]);
      int kk = k0c + 4 * hi;
      float sv = acc[t][r] + bv;
      sv = (kk < 196) ? sv : -1e30f;
      acc[t][r] = sv;
      mx = fmaxf(mx, sv);
    }
  mx = fmaxf(mx, __shfl_xor(mx, 32));

  // ---- exp + sum + pack P to bf16 A-fragments (frees the f32 scores) ----
  float sum = 0.f;
  u32 pw[7][8];
#pragma unroll
  for (int t = 0; t < 7; ++t) {
    float p[16];
#pragma unroll
    for (int r = 0; r < 16; ++r) { p[r] = __expf(acc[t][r] - mx); sum += p[r]; }
#pragma unroll
    for (int s2 = 0; s2 < 2; ++s2) {
      u32 a0 = packbf(p[s2 * 8 + 0], p[s2 * 8 + 1]);
      u32 a1 = packbf(p[s2 * 8 + 2], p[s2 * 8 + 3]);
      u32 b0 = packbf(p[s2 * 8 + 4], p[s2 * 8 + 5]);
      u32 b1 = packbf(p[s2 * 8 + 6], p[s2 * 8 + 7]);
      u32 xa0 = __shfl_xor(a0, 32), xa1 = __shfl_xor(a1, 32);
      u32 xb0 = __shfl_xor(b0, 32), xb1 = __shfl_xor(b1, 32);
      pw[t][s2 * 4 + 0] = hi ? xb0 : a0;
      pw[t][s2 * 4 + 1] = hi ? xb1 : a1;
      pw[t][s2 * 4 + 2] = hi ? b0 : xa0;
      pw[t][s2 * 4 + 3] = hi ? b1 : xa1;
    }
  }
  sum += __shfl_xor(sum, 32);
  if (lane < 32) invL[w * 32 + l31] = 1.0f / sum;
  __builtin_amdgcn_sched_barrier(0);

  // ---- PV: out[q][d] = sum_k P[q][k] V[k][d] ----
  f32x16 oacc[3] = {};
#pragma unroll
  for (int t = 0; t < 7; ++t)
#pragma unroll
    for (int s2 = 0; s2 < 2; ++s2) {
      union { u32 u[4]; bf16x8 v; } pf;
      pf.u[0] = pw[t][s2 * 4 + 0];
      pf.u[1] = pw[t][s2 * 4 + 1];
      pf.u[2] = pw[t][s2 * 4 + 2];
      pf.u[3] = pw[t][s2 * 4 + 3];
#pragma unroll
      for (int dt = 0; dt < 3; ++dt) {
        bf16x8 vf = *(const bf16x8*)&Vt[(dt * 32 + l31) * 232 + t * 32 + s2 * 16 + hi * 8];
        oacc[dt] = __builtin_amdgcn_mfma_f32_32x32x16_bf16(pf.v, vf, oacc[dt], 0, 0, 0);
      }
    }

  // ---- epilogue: divide by softmax sum, store bf16 [b, s, h*80+d] ----
  const int bb = bh >> 4, hh = bh & 15;
#pragma unroll
  for (int r = 0; r < 16; ++r) {
    int crow = (r & 3) + 8 * (r >> 2) + 4 * hi;
    int qrow = w * 32 + crow;
    if (qrow < 196) {
      float inv = invL[w * 32 + crow];
#pragma unroll
      for (int dt = 0; dt < 3; ++dt) {
        int d = dt * 32 + l31;
        if (d < 80) {
          size_t off = ((size_t)bb * 196 + qrow) * 1280 + hh * 80 + d;
          outb[off] = f2bf(oacc[dt][r] * inv);
        }
      }
    }
  }
}

// ------------------------------ launch -------------------------------------
extern "C" void kernel_launch(void* const* d_in, const int* in_sizes, int n_in,
                              void* d_out, int out_size, void* d_ws, size_t ws_size,
                              hipStream_t stream)
{
  (void)in_sizes; (void)n_in; (void)out_size; (void)ws_size;
  const float* hs    = (const float*)d_in[0];
  const float* wqkv  = (const float*)d_in[1];
  const float* bqkv  = (const float*)d_in[2];
  const float* wproj = (const float*)d_in[3];
  const float* bproj = (const float*)d_in[4];
  const float* relh  = (const float*)d_in[5];
  const float* relw  = (const float*)d_in[6];
  float* out = (float*)d_out;

  // workspace layout (bytes); total ~503 MiB
  char* ws = (char*)d_ws;
  u16* Xb    = (u16*)(ws);                 // 128,450,560  X_bf16, later attn_out
  u16* Wqb   = (u16*)(ws + 128450560);     //   9,830,400
  u16* Wpb   = (u16*)(ws + 138280960);     //   3,276,800
  u16* qb    = (u16*)(ws + 141557760);     // 128,450,560
  u16* kb    = (u16*)(ws + 270008320);     // 128,450,560
  u16* vb    = (u16*)(ws + 398458880);     // 128,450,560
  u16* relhb = (u16*)(ws + 526909440);     //       4,320
  u16* relwb = (u16*)(ws + 526913760);     //       4,320

  cvt_kernel<<<2048, 256, 0, stream>>>(hs,    Xb,  16056320);
  cvt_kernel<<<512,  256, 0, stream>>>(wqkv,  Wqb, 1228800);
  cvt_kernel<<<256,  256, 0, stream>>>(wproj, Wpb, 409600);
  cvt_kernel<<<1,    256, 0, stream>>>(relh,  relhb, 540);
  cvt_kernel<<<1,    256, 0, stream>>>(relw,  relwb, 540);

  // QKV: grid 30x392 = 11760 blocks (%8==0 -> bijective XCD swizzle, cpx=1470)
  gemm_bt<0><<<11760, 256, 0, stream>>>(Xb, Wqb, bqkv, qb, kb, vb, nullptr, 30, 1470);

  attn_kernel<<<4096, 448, 0, stream>>>(qb, kb, vb, relhb, relwb, Xb);

  // proj: grid 10x392 = 3920 blocks (%8==0, cpx=490)
  gemm_bt<1><<<3920, 256, 0, stream>>>(Xb, Wpb, bproj, nullptr, nullptr, nullptr, out, 10, 490);
}